// Round 10
// baseline (208.819 us; speedup 1.0000x reference)
//
#include <hip/hip_runtime.h>
#include <stdint.h>

#define B_ 4
#define T_ 2048
#define S_ 2048
#define E_ 512
#define H_ 8
#define D_ 64

using bf16x8 = __attribute__((ext_vector_type(8))) short;
using bf16x4 = __attribute__((ext_vector_type(4))) short;
using f32x4  = __attribute__((ext_vector_type(4))) float;

__device__ __forceinline__ unsigned short f2bf(float f) {
  unsigned u = __float_as_uint(f);
  u += 0x7fffu + ((u >> 16) & 1u);          // round-to-nearest-even
  return (unsigned short)(u >> 16);
}

__device__ __forceinline__ float sigmoidf_(float x) {
  return 1.0f / (1.0f + __expf(-x));
}

// legacy K=16 bf16 MFMA: A/B = 4 bf16 (2 VGPR), layout row=lane&15, k=(lane>>4)*4+e
__device__ __forceinline__ f32x4 mfma16x16x16(bf16x4 a, bf16x4 b, f32x4 c) {
#if __has_builtin(__builtin_amdgcn_mfma_f32_16x16x16bf16_1k)
  return __builtin_amdgcn_mfma_f32_16x16x16bf16_1k(a, b, c, 0, 0, 0);
#else
  asm("v_mfma_f32_16x16x16_bf16 %0, %1, %2, %0" : "+v"(c) : "v"(a), "v"(b));
  return c;
#endif
}

// async global->LDS, 16B per lane. LDS dest = wave-uniform base + lane*16.
__device__ __forceinline__ void gl16(const void* g, void* l) {
  __builtin_amdgcn_global_load_lds(
      (const __attribute__((address_space(1))) unsigned*)g,
      (__attribute__((address_space(3))) unsigned*)l,
      16, 0, 0);
}

// T2 swizzle for [R][64 bf16] (128B-row) LDS tiles:
// physical byte-in-row = logical byte-in-row ^ ((row&7)<<4).
__device__ __forceinline__ int swzi(int row, int ebyte) {
  return row * 64 + ((ebyte ^ ((row & 7) << 4)) >> 1);
}

// ---------------------------------------------------------------- converts
__global__ __launch_bounds__(256) void cvt3_bf16(
    const float* __restrict__ a, const float* __restrict__ b, const float* __restrict__ c,
    unsigned short* __restrict__ oa, unsigned short* __restrict__ ob,
    unsigned short* __restrict__ oc, int n4) {
  int seg = blockIdx.x >> 9;
  const float* in = (seg == 0) ? a : (seg == 1) ? b : c;
  unsigned short* out = (seg == 0) ? oa : (seg == 1) ? ob : oc;
  int i = (blockIdx.x & 511) * 256 + threadIdx.x;
  for (; i < n4; i += 512 * 256) {
    float4 v = ((const float4*)in)[i];
    ushort4 o;
    o.x = f2bf(v.x); o.y = f2bf(v.y); o.z = f2bf(v.z); o.w = f2bf(v.w);
    ((ushort4*)out)[i] = o;
  }
}

__global__ __launch_bounds__(256) void cvt4_bf16(
    const float* __restrict__ a, const float* __restrict__ b,
    const float* __restrict__ c, const float* __restrict__ d,
    unsigned short* __restrict__ oa, unsigned short* __restrict__ ob,
    unsigned short* __restrict__ oc, unsigned short* __restrict__ od, int n4) {
  int seg = blockIdx.x >> 7;
  const float* in = (seg == 0) ? a : (seg == 1) ? b : (seg == 2) ? c : d;
  unsigned short* out = (seg == 0) ? oa : (seg == 1) ? ob : (seg == 2) ? oc : od;
  int i = (blockIdx.x & 127) * 256 + threadIdx.x;
  for (; i < n4; i += 128 * 256) {
    float4 v = ((const float4*)in)[i];
    ushort4 o;
    o.x = f2bf(v.x); o.y = f2bf(v.y); o.z = f2bf(v.z); o.w = f2bf(v.w);
    ((ushort4*)out)[i] = o;
  }
}

// ---------------------------------------------------------------- GEMM
// C[M,N] = A[M,512] * W[N,512]^T  (NT gemm, K=512), 128x64 tile, BK=64.
#define EPI_LH  0
#define EPI_VT  1
#define EPI_F32 2

template <int EPI>
__global__ __launch_bounds__(256) void gemm_nt(
    const unsigned short* __restrict__ A,
    const unsigned short* __restrict__ W,
    const float* __restrict__ bias,
    void* __restrict__ outp,
    const float* __restrict__ rptr,
    float oscale,
    int nTN) {
  __shared__ unsigned short As[2][128 * 64];   // 32 KB
  __shared__ unsigned short Bs[2][64 * 64];    // 16 KB

  int bid = ((blockIdx.x & 7) << 6) + (blockIdx.x >> 3);  // 512 blocks, 8 XCDs
  int tid = threadIdx.x;
  int lane = tid & 63, wid = tid >> 6;
  int bm = bid / nTN, bn = bid % nTN;
  int m0 = bm * 128, n0 = bn * 64;

  f32x4 acc[4][2] = {};

  int rowc = tid >> 3;                                  // tile-local row / chunk
  int kswz = ((tid & 7) ^ (rowc & 7)) << 4;             // pre-swizzled source byte col

  auto stage = [&](int buf, int kt) {
#pragma unroll
    for (int c = 0; c < 4; ++c) {
      const char* ga = (const char*)A + (size_t)(m0 + c * 32 + rowc) * 1024 + kt * 128 + kswz;
      gl16(ga, (char*)&As[buf][0] + c * 4096 + (wid << 10));
    }
#pragma unroll
    for (int c = 0; c < 2; ++c) {
      const char* gw = (const char*)W + (size_t)(n0 + c * 32 + rowc) * 1024 + kt * 128 + kswz;
      gl16(gw, (char*)&Bs[buf][0] + c * 4096 + (wid << 10));
    }
  };

  stage(0, 0);

  int wm = wid >> 1, wn = wid & 1;       // 2x2 waves; each wave 64(M) x 32(N)
  int fr = lane & 15, fg = lane >> 4;

  for (int kt = 0; kt < 8; ++kt) {
    __syncthreads();                     // staged tile `kt` ready (vmcnt drained)
    if (kt < 7) stage((kt + 1) & 1, kt + 1);
    int buf = kt & 1;
#pragma unroll
    for (int ks = 0; ks < 2; ++ks) {
      bf16x8 a[4], b[2];
#pragma unroll
      for (int mi = 0; mi < 4; ++mi)
        a[mi] = *(const bf16x8*)&As[buf][swzi(wm * 64 + mi * 16 + fr, ks * 64 + fg * 16)];
#pragma unroll
      for (int ni = 0; ni < 2; ++ni)
        b[ni] = *(const bf16x8*)&Bs[buf][swzi(wn * 32 + ni * 16 + fr, ks * 64 + fg * 16)];
#pragma unroll
      for (int mi = 0; mi < 4; ++mi)
#pragma unroll
        for (int ni = 0; ni < 2; ++ni)
          acc[mi][ni] = __builtin_amdgcn_mfma_f32_16x16x32_bf16(a[mi], b[ni], acc[mi][ni], 0, 0, 0);
    }
  }

  float rs = 0.f;
  if constexpr (EPI == EPI_LH) rs = 4.0f * sigmoidf_(rptr[0]) * oscale;

#pragma unroll
  for (int mi = 0; mi < 4; ++mi) {
#pragma unroll
    for (int ni = 0; ni < 2; ++ni) {
#pragma unroll
      for (int i = 0; i < 4; ++i) {
        int gm = m0 + wm * 64 + mi * 16 + fg * 4 + i;   // C row
        int gn = n0 + wn * 32 + ni * 16 + fr;           // C col
        float x = acc[mi][ni][i];
        if constexpr (EPI == EPI_LH) {
          x += bias[gn];
          float xn = sigmoidf_(x);
          float val = rs * xn * (1.0f - xn);
          int b = gm >> 11, t = gm & 2047, h = gn >> 6, d = gn & 63;
          ((unsigned short*)outp)[((size_t)(b * H_ + h) * T_ + t) * D_ + d] = f2bf(val);
        } else if constexpr (EPI == EPI_VT) {
          x += bias[gm];                                // bias indexed by e = row
          int h = gm >> 6, d = gm & 63, b = gn >> 11, s = gn & 2047;
          ((unsigned short*)outp)[((size_t)(b * H_ + h) * D_ + d) * S_ + s] = f2bf(x);
        } else {
          x += bias[gn];
          ((float*)outp)[(size_t)gm * E_ + gn] = x;
        }
      }
    }
  }
}

// ---------------------------------------------------------------- flash attention
// Q,K are logistic-map outputs => all scores >= 0, s_log2 <= ~11, exp2(s) <= ~2k,
// l <= ~4e6: NO max subtraction needed (scale cancels in O/l). P = exp2(s) directly.
// Per KV tile (64 kv) compute step; CB = compile-time LDS buffer base (imm-folded).
template <int CB>
__device__ __forceinline__ void tile_step(
    char* sm, int koff0, int koff1, const int (&voff)[4],
    const bf16x8 (&qa)[2][2], f32x4 (&acco)[2][4], float (&lst)[2]) {
  bf16x8 kb[4][2];
#pragma unroll
  for (int ni = 0; ni < 4; ++ni) {
    kb[ni][0] = *(const bf16x8*)(sm + CB + ni * 2048 + koff0);
    kb[ni][1] = *(const bf16x8*)(sm + CB + ni * 2048 + koff1);
  }
  f32x4 st[4][2];
#pragma unroll
  for (int ni = 0; ni < 4; ++ni)
#pragma unroll
    for (int mi = 0; mi < 2; ++mi) st[ni][mi] = f32x4{0.f, 0.f, 0.f, 0.f};

  __builtin_amdgcn_s_setprio(1);
#pragma unroll
  for (int ni = 0; ni < 4; ++ni)
#pragma unroll
    for (int mi = 0; mi < 2; ++mi) {
      st[ni][mi] = __builtin_amdgcn_mfma_f32_16x16x32_bf16(kb[ni][0], qa[mi][0], st[ni][mi], 0, 0, 0);
      st[ni][mi] = __builtin_amdgcn_mfma_f32_16x16x32_bf16(kb[ni][1], qa[mi][1], st[ni][mi], 0, 0, 0);
    }
  __builtin_amdgcn_s_setprio(0);

  // ---- P = exp2(s) (no max tracking; all s >= 0, bounded)
  union PU { unsigned u[2]; bf16x4 v; };
  bf16x4 pfr[2][4];
#pragma unroll
  for (int mi = 0; mi < 2; ++mi) {
    float sum = 0.f;
#pragma unroll
    for (int ni = 0; ni < 4; ++ni) {
      float p0 = __builtin_amdgcn_exp2f(st[ni][mi][0]);
      float p1 = __builtin_amdgcn_exp2f(st[ni][mi][1]);
      float p2 = __builtin_amdgcn_exp2f(st[ni][mi][2]);
      float p3 = __builtin_amdgcn_exp2f(st[ni][mi][3]);
      sum += (p0 + p1) + (p2 + p3);
      PU pu;
      asm("v_cvt_pk_bf16_f32 %0, %1, %2" : "=v"(pu.u[0]) : "v"(p0), "v"(p1));
      asm("v_cvt_pk_bf16_f32 %0, %1, %2" : "=v"(pu.u[1]) : "v"(p2), "v"(p3));
      pfr[mi][ni] = pu.v;
    }
    sum += __shfl_xor(sum, 16);
    sum += __shfl_xor(sum, 32);
    lst[mi] += sum;
  }

  // ---- O^T += V^T P^T
  __builtin_amdgcn_s_setprio(1);
#pragma unroll
  for (int nd = 0; nd < 4; ++nd)
#pragma unroll
    for (int ni = 0; ni < 4; ++ni) {
      bf16x4 vf = *(const bf16x4*)(sm + CB + nd * 2048 + voff[ni]);
#pragma unroll
      for (int mi = 0; mi < 2; ++mi)
        acco[mi][nd] = mfma16x16x16(vf, pfr[mi][ni], acco[mi][nd]);
    }
  __builtin_amdgcn_s_setprio(0);
}

// grid: 512 blocks = 32 (b,h) * 16 Q-tiles of 128 rows. 4 waves * 32 rows.
// 2 KV buffers of 16KB (K 8KB + V 8KB) = 32KB LDS -> 4 blocks/CU (16 waves/CU),
// forced by __launch_bounds__(256,4) (VGPR <= 128). Q stages through b1 then
// lives in registers. One barrier per tile; stage t+1 while computing t.
// XCD-bijective swizzle (512%8==0): 64 consecutive wgid (4 bh, KV 2MB) per XCD L2.
__global__ __launch_bounds__(256, 4) void attn_flash(
    const unsigned short* __restrict__ qp,   // [B,H,T,D], pre-scaled by 0.125*log2e
    const unsigned short* __restrict__ kp,   // [B,H,S,D]
    const unsigned short* __restrict__ vtp,  // [B,H,D,S]
    unsigned short* __restrict__ attno) {    // [B*T, E]
  __shared__ __align__(16) char smem[32768];

  int tid = threadIdx.x, lane = tid & 63, wid = tid >> 6;
  int wgid = ((blockIdx.x & 7) << 6) + (blockIdx.x >> 3);  // 512 blocks, 8 XCDs
  int tt = wgid & 15, bh = wgid >> 4;
  const char* qh = (const char*)qp + ((size_t)bh * T_ + tt * 128) * 128;
  const char* kh = (const char*)kp + (size_t)bh * S_ * 128;
  const char* vh = (const char*)vtp + (size_t)bh * D_ * S_ * 2;

  int rowc = tid >> 3;
  int kswz = ((tid & 7) ^ (rowc & 7)) << 4;

#define STAGE_K(SB, IT) { \
    gl16(kh + (size_t)((IT) * 64 + rowc) * 128 + kswz, smem + (SB) + (wid << 10)); \
    gl16(kh + (size_t)((IT) * 64 + 32 + rowc) * 128 + kswz, smem + (SB) + 4096 + (wid << 10)); }
#define STAGE_V(SB, IT) { \
    gl16(vh + (size_t)rowc * 4096 + (IT) * 128 + kswz, smem + (SB) + 8192 + (wid << 10)); \
    gl16(vh + (size_t)(32 + rowc) * 4096 + (IT) * 128 + kswz, smem + (SB) + 12288 + (wid << 10)); }

  // prologue: KV0 -> b0, Q (16KB) -> b1
  STAGE_K(0, 0) STAGE_V(0, 0)
#pragma unroll
  for (int c = 0; c < 4; ++c)
    gl16(qh + (size_t)(c * 32 + rowc) * 128 + kswz, smem + 16384 + c * 4096 + (wid << 10));

  int fr = lane & 15, fg = (lane >> 4) & 3;
  int qrb = wid * 32;
  // hoisted per-lane swizzled LDS byte offsets (col bytes: ks*64 + fg*16, XOR (fr&7)<<4)
  int koff0 = fr * 128 + ((fg * 16) ^ ((fr & 7) << 4));
  int koff1 = fr * 128 + ((64 + fg * 16) ^ ((fr & 7) << 4));
  int voff[4];
#pragma unroll
  for (int ni = 0; ni < 4; ++ni)
    voff[ni] = 8192 + fr * 128 + ((ni * 32 + fg * 8) ^ ((fr & 7) << 4));

  __syncthreads();   // KV0 + Q landed (vmcnt drained)

  // Q fragments -> registers; b1 then becomes the second KV buffer
  bf16x8 qa[2][2];
#pragma unroll
  for (int mi = 0; mi < 2; ++mi) {
    qa[mi][0] = *(const bf16x8*)(smem + 16384 + (qrb + mi * 16) * 128 + koff0);
    qa[mi][1] = *(const bf16x8*)(smem + 16384 + (qrb + mi * 16) * 128 + koff1);
  }
  __syncthreads();   // ALL waves' Q reads done before b1 is overwritten

  f32x4 acco[2][4] = {};
  float lst[2] = {0.f, 0.f};

  // stage KV1 -> b1; compute tile 0 while it lands
  STAGE_K(16384, 1) STAGE_V(16384, 1)
  tile_step<0>(smem, koff0, koff1, voff, qa, acco, lst);        // t=0

#pragma unroll 1
  for (int pp = 0; pp <= 14; ++pp) {
    int ta = pp * 2;
    __syncthreads();                               // KV(ta+1) landed in b1; b0 reads done
    STAGE_K(0, ta + 2) STAGE_V(0, ta + 2)
    tile_step<16384>(smem, koff0, koff1, voff, qa, acco, lst);  // t=ta+1
    __syncthreads();                               // KV(ta+2) landed in b0; b1 reads done
    STAGE_K(16384, ta + 3) STAGE_V(16384, ta + 3)
    tile_step<0>(smem, koff0, koff1, voff, qa, acco, lst);      // t=ta+2
  }
  __syncthreads();                                 // KV31 landed in b1
  tile_step<16384>(smem, koff0, koff1, voff, qa, acco, lst);    // t=31

  // ---- epilogue: O^T lane holds q=16mi+fr, d=16nd+4fg+reg; divide by l, 8B stores
  int b = bh >> 3, h = bh & 7;
#pragma unroll
  for (int mi = 0; mi < 2; ++mi) {
    float rl = 1.0f / lst[mi];
    int t = tt * 128 + qrb + mi * 16 + fr;
    unsigned short* rowp = attno + (size_t)(b * T_ + t) * E_ + h * 64;
#pragma unroll
    for (int nd = 0; nd < 4; ++nd) {
      ushort4 o;
      o.x = f2bf(acco[mi][nd][0] * rl);
      o.y = f2bf(acco[mi][nd][1] * rl);
      o.z = f2bf(acco[mi][nd][2] * rl);
      o.w = f2bf(acco[mi][nd][3] * rl);
      *(ushort4*)(rowp + nd * 16 + fg * 4) = o;
    }
  }
#undef STAGE_K
#undef STAGE_V
}

// ---------------------------------------------------------------- launch
extern "C" void kernel_launch(void* const* d_in, const int* in_sizes, int n_in,
                              void* d_out, int out_size, void* d_ws, size_t ws_size,
                              hipStream_t stream) {
  const float* query = (const float*)d_in[0];
  const float* key_  = (const float*)d_in[1];
  const float* value = (const float*)d_in[2];
  const float* Wq    = (const float*)d_in[3];
  const float* bq    = (const float*)d_in[4];
  const float* Wk    = (const float*)d_in[5];
  const float* bk    = (const float*)d_in[6];
  const float* Wv    = (const float*)d_in[7];
  const float* bv    = (const float*)d_in[8];
  const float* Wo    = (const float*)d_in[9];
  const float* bo    = (const float*)d_in[10];
  const float* r     = (const float*)d_in[11];

  char* ws = (char*)d_ws;
  unsigned short* qb    = (unsigned short*)(ws + 0);          //  8 MiB  query bf16
  unsigned short* kb    = (unsigned short*)(ws + 8388608);    //  8 MiB  key bf16
  unsigned short* vb    = (unsigned short*)(ws + 16777216);   //  8 MiB  value bf16
  unsigned short* wqb   = (unsigned short*)(ws + 25165824);   // 512 KiB
  unsigned short* wkb   = (unsigned short*)(ws + 25690112);
  unsigned short* wvb   = (unsigned short*)(ws + 26214400);
  unsigned short* wob   = (unsigned short*)(ws + 26738688);
  unsigned short* qp    = (unsigned short*)(ws + 27262976);   //  8 MiB  [B,H,T,D]
  unsigned short* kp    = (unsigned short*)(ws + 35651584);   //  8 MiB  [B,H,S,D]
  unsigned short* vtp   = (unsigned short*)(ws + 44040192);   //  8 MiB  [B,H,D,S]
  unsigned short* attno = (unsigned short*)(ws + 52428800);   //  8 MiB  [B*T, E]

  cvt3_bf16<<<1536, 256, 0, stream>>>(query, key_, value, qb, kb, vb, (B_ * T_ * E_) / 4);
  cvt4_bf16<<<512, 256, 0, stream>>>(Wq, Wk, Wv, Wo, wqb, wkb, wvb, wob, (E_ * E_) / 4);

  const float SCLQ = 0.125f * 1.44269504089f;  // fold 1/sqrt(D) * log2(e) into Q

  // Q = logistic(query Wq^T + bq) * SCLQ  -> [B,H,T,D]
  gemm_nt<EPI_LH><<<512, 256, 0, stream>>>(qb, wqb, bq, qp, r, SCLQ, 8);
  // K = logistic(key Wk^T + bk)           -> [B,H,S,D]
  gemm_nt<EPI_LH><<<512, 256, 0, stream>>>(kb, wkb, bk, kp, r, 1.0f, 8);
  // V^T = Wv value^T + bv                 -> [B,H,D,S]  (swapped NT gemm)
  gemm_nt<EPI_VT><<<512, 256, 0, stream>>>(wvb, vb, bv, vtp, r, 1.0f, 128);

  attn_flash<<<512, 256, 0, stream>>>(qp, kp, vtp, attno);

  // out = attno Wo^T + bo  (fp32)
  gemm_nt<EPI_F32><<<512, 256, 0, stream>>>(attno, wob, bo, d_out, r, 1.0f, 8);
}

// Round 11
// 114.178 us; speedup vs baseline: 1.8289x; 1.8289x over previous
//
#include <hip/hip_runtime.h>
#include <stdint.h>

#define B_ 4
#define T_ 2048
#define S_ 2048
#define E_ 512
#define H_ 8
#define D_ 64

using bf16x8 = __attribute__((ext_vector_type(8))) short;
using bf16x4 = __attribute__((ext_vector_type(4))) short;
using f32x4  = __attribute__((ext_vector_type(4))) float;

__device__ __forceinline__ unsigned short f2bf(float f) {
  unsigned u = __float_as_uint(f);
  u += 0x7fffu + ((u >> 16) & 1u);          // round-to-nearest-even
  return (unsigned short)(u >> 16);
}

__device__ __forceinline__ float sigmoidf_(float x) {
  return 1.0f / (1.0f + __expf(-x));
}

// legacy K=16 bf16 MFMA: A/B = 4 bf16 (2 VGPR), layout row=lane&15, k=(lane>>4)*4+e
__device__ __forceinline__ f32x4 mfma16x16x16(bf16x4 a, bf16x4 b, f32x4 c) {
#if __has_builtin(__builtin_amdgcn_mfma_f32_16x16x16bf16_1k)
  return __builtin_amdgcn_mfma_f32_16x16x16bf16_1k(a, b, c, 0, 0, 0);
#else
  asm("v_mfma_f32_16x16x16_bf16 %0, %1, %2, %0" : "+v"(c) : "v"(a), "v"(b));
  return c;
#endif
}

// async global->LDS, 16B per lane. LDS dest = wave-uniform base + lane*16.
__device__ __forceinline__ void gl16(const void* g, void* l) {
  __builtin_amdgcn_global_load_lds(
      (const __attribute__((address_space(1))) unsigned*)g,
      (__attribute__((address_space(3))) unsigned*)l,
      16, 0, 0);
}

// T2 swizzle for [R][64 bf16] (128B-row) LDS tiles:
// physical byte-in-row = logical byte-in-row ^ ((row&7)<<4).
__device__ __forceinline__ int swzi(int row, int ebyte) {
  return row * 64 + ((ebyte ^ ((row & 7) << 4)) >> 1);
}

// ---------------------------------------------------------------- converts
__global__ __launch_bounds__(256) void cvt3_bf16(
    const float* __restrict__ a, const float* __restrict__ b, const float* __restrict__ c,
    unsigned short* __restrict__ oa, unsigned short* __restrict__ ob,
    unsigned short* __restrict__ oc, int n4) {
  int seg = blockIdx.x >> 9;
  const float* in = (seg == 0) ? a : (seg == 1) ? b : c;
  unsigned short* out = (seg == 0) ? oa : (seg == 1) ? ob : oc;
  int i = (blockIdx.x & 511) * 256 + threadIdx.x;
  for (; i < n4; i += 512 * 256) {
    float4 v = ((const float4*)in)[i];
    ushort4 o;
    o.x = f2bf(v.x); o.y = f2bf(v.y); o.z = f2bf(v.z); o.w = f2bf(v.w);
    ((ushort4*)out)[i] = o;
  }
}

__global__ __launch_bounds__(256) void cvt4_bf16(
    const float* __restrict__ a, const float* __restrict__ b,
    const float* __restrict__ c, const float* __restrict__ d,
    unsigned short* __restrict__ oa, unsigned short* __restrict__ ob,
    unsigned short* __restrict__ oc, unsigned short* __restrict__ od, int n4) {
  int seg = blockIdx.x >> 7;
  const float* in = (seg == 0) ? a : (seg == 1) ? b : (seg == 2) ? c : d;
  unsigned short* out = (seg == 0) ? oa : (seg == 1) ? ob : (seg == 2) ? oc : od;
  int i = (blockIdx.x & 127) * 256 + threadIdx.x;
  for (; i < n4; i += 128 * 256) {
    float4 v = ((const float4*)in)[i];
    ushort4 o;
    o.x = f2bf(v.x); o.y = f2bf(v.y); o.z = f2bf(v.z); o.w = f2bf(v.w);
    ((ushort4*)out)[i] = o;
  }
}

// ---------------------------------------------------------------- GEMM
// C[M,N] = A[M,512] * W[N,512]^T  (NT gemm, K=512), 128x64 tile, BK=64.
#define EPI_LH  0
#define EPI_VT  1
#define EPI_F32 2

template <int EPI>
__global__ __launch_bounds__(256) void gemm_nt(
    const unsigned short* __restrict__ A,
    const unsigned short* __restrict__ W,
    const float* __restrict__ bias,
    void* __restrict__ outp,
    const float* __restrict__ rptr,
    float oscale,
    int nTN) {
  __shared__ unsigned short As[2][128 * 64];   // 32 KB
  __shared__ unsigned short Bs[2][64 * 64];    // 16 KB

  int bid = ((blockIdx.x & 7) << 6) + (blockIdx.x >> 3);  // 512 blocks, 8 XCDs
  int tid = threadIdx.x;
  int lane = tid & 63, wid = tid >> 6;
  int bm = bid / nTN, bn = bid % nTN;
  int m0 = bm * 128, n0 = bn * 64;

  f32x4 acc[4][2] = {};

  int rowc = tid >> 3;                                  // tile-local row / chunk
  int kswz = ((tid & 7) ^ (rowc & 7)) << 4;             // pre-swizzled source byte col

  auto stage = [&](int buf, int kt) {
#pragma unroll
    for (int c = 0; c < 4; ++c) {
      const char* ga = (const char*)A + (size_t)(m0 + c * 32 + rowc) * 1024 + kt * 128 + kswz;
      gl16(ga, (char*)&As[buf][0] + c * 4096 + (wid << 10));
    }
#pragma unroll
    for (int c = 0; c < 2; ++c) {
      const char* gw = (const char*)W + (size_t)(n0 + c * 32 + rowc) * 1024 + kt * 128 + kswz;
      gl16(gw, (char*)&Bs[buf][0] + c * 4096 + (wid << 10));
    }
  };

  stage(0, 0);

  int wm = wid >> 1, wn = wid & 1;       // 2x2 waves; each wave 64(M) x 32(N)
  int fr = lane & 15, fg = lane >> 4;

  for (int kt = 0; kt < 8; ++kt) {
    __syncthreads();                     // staged tile `kt` ready (vmcnt drained)
    if (kt < 7) stage((kt + 1) & 1, kt + 1);
    int buf = kt & 1;
#pragma unroll
    for (int ks = 0; ks < 2; ++ks) {
      bf16x8 a[4], b[2];
#pragma unroll
      for (int mi = 0; mi < 4; ++mi)
        a[mi] = *(const bf16x8*)&As[buf][swzi(wm * 64 + mi * 16 + fr, ks * 64 + fg * 16)];
#pragma unroll
      for (int ni = 0; ni < 2; ++ni)
        b[ni] = *(const bf16x8*)&Bs[buf][swzi(wn * 32 + ni * 16 + fr, ks * 64 + fg * 16)];
#pragma unroll
      for (int mi = 0; mi < 4; ++mi)
#pragma unroll
        for (int ni = 0; ni < 2; ++ni)
          acc[mi][ni] = __builtin_amdgcn_mfma_f32_16x16x32_bf16(a[mi], b[ni], acc[mi][ni], 0, 0, 0);
    }
  }

  float rs = 0.f;
  if constexpr (EPI == EPI_LH) rs = 4.0f * sigmoidf_(rptr[0]) * oscale;

#pragma unroll
  for (int mi = 0; mi < 4; ++mi) {
#pragma unroll
    for (int ni = 0; ni < 2; ++ni) {
#pragma unroll
      for (int i = 0; i < 4; ++i) {
        int gm = m0 + wm * 64 + mi * 16 + fg * 4 + i;   // C row
        int gn = n0 + wn * 32 + ni * 16 + fr;           // C col
        float x = acc[mi][ni][i];
        if constexpr (EPI == EPI_LH) {
          x += bias[gn];
          float xn = sigmoidf_(x);
          float val = rs * xn * (1.0f - xn);
          int b = gm >> 11, t = gm & 2047, h = gn >> 6, d = gn & 63;
          ((unsigned short*)outp)[((size_t)(b * H_ + h) * T_ + t) * D_ + d] = f2bf(val);
        } else if constexpr (EPI == EPI_VT) {
          x += bias[gm];                                // bias indexed by e = row
          int h = gm >> 6, d = gm & 63, b = gn >> 11, s = gn & 2047;
          ((unsigned short*)outp)[((size_t)(b * H_ + h) * D_ + d) * S_ + s] = f2bf(x);
        } else {
          x += bias[gn];
          ((float*)outp)[(size_t)gm * E_ + gn] = x;
        }
      }
    }
  }
}

// ---------------------------------------------------------------- flash attention
// Q,K are logistic-map outputs => all scores >= 0, s_log2 <= ~11, exp2(s) <= ~2k,
// l <= ~4e6: NO max subtraction needed (scale cancels in O/l). P = exp2(s) directly.
// Per KV tile (64 kv) compute step; CB = compile-time LDS buffer base (imm-folded).
template <int CB>
__device__ __forceinline__ void tile_step(
    char* sm, int koff0, int koff1, const int (&voff)[4],
    const bf16x8 (&qa)[2][2], f32x4 (&acco)[2][4], float (&lst)[2]) {
  bf16x8 kb[4][2];
#pragma unroll
  for (int ni = 0; ni < 4; ++ni) {
    kb[ni][0] = *(const bf16x8*)(sm + CB + ni * 2048 + koff0);
    kb[ni][1] = *(const bf16x8*)(sm + CB + ni * 2048 + koff1);
  }
  f32x4 st[4][2];
#pragma unroll
  for (int ni = 0; ni < 4; ++ni)
#pragma unroll
    for (int mi = 0; mi < 2; ++mi) st[ni][mi] = f32x4{0.f, 0.f, 0.f, 0.f};

  __builtin_amdgcn_s_setprio(1);
#pragma unroll
  for (int ni = 0; ni < 4; ++ni)
#pragma unroll
    for (int mi = 0; mi < 2; ++mi) {
      st[ni][mi] = __builtin_amdgcn_mfma_f32_16x16x32_bf16(kb[ni][0], qa[mi][0], st[ni][mi], 0, 0, 0);
      st[ni][mi] = __builtin_amdgcn_mfma_f32_16x16x32_bf16(kb[ni][1], qa[mi][1], st[ni][mi], 0, 0, 0);
    }
  __builtin_amdgcn_s_setprio(0);

  // ---- P = exp2(s) (no max tracking; all s >= 0, bounded)
  union PU { unsigned u[2]; bf16x4 v; };
  bf16x4 pfr[2][4];
#pragma unroll
  for (int mi = 0; mi < 2; ++mi) {
    float sum = 0.f;
#pragma unroll
    for (int ni = 0; ni < 4; ++ni) {
      float p0 = __builtin_amdgcn_exp2f(st[ni][mi][0]);
      float p1 = __builtin_amdgcn_exp2f(st[ni][mi][1]);
      float p2 = __builtin_amdgcn_exp2f(st[ni][mi][2]);
      float p3 = __builtin_amdgcn_exp2f(st[ni][mi][3]);
      sum += (p0 + p1) + (p2 + p3);
      PU pu;
      asm("v_cvt_pk_bf16_f32 %0, %1, %2" : "=v"(pu.u[0]) : "v"(p0), "v"(p1));
      asm("v_cvt_pk_bf16_f32 %0, %1, %2" : "=v"(pu.u[1]) : "v"(p2), "v"(p3));
      pfr[mi][ni] = pu.v;
    }
    sum += __shfl_xor(sum, 16);
    sum += __shfl_xor(sum, 32);
    lst[mi] += sum;
  }

  // ---- O^T += V^T P^T
  __builtin_amdgcn_s_setprio(1);
#pragma unroll
  for (int nd = 0; nd < 4; ++nd)
#pragma unroll
    for (int ni = 0; ni < 4; ++ni) {
      bf16x4 vf = *(const bf16x4*)(sm + CB + nd * 2048 + voff[ni]);
#pragma unroll
      for (int mi = 0; mi < 2; ++mi)
        acco[mi][nd] = mfma16x16x16(vf, pfr[mi][ni], acco[mi][nd]);
    }
  __builtin_amdgcn_s_setprio(0);
}

// grid: 512 blocks = 32 (b,h) * 16 Q-tiles of 128 rows. 4 waves * 32 rows.
// 2 KV buffers of 16KB (K 8KB + V 8KB) = 32KB LDS. NO launch_bounds cap:
// at ~116 VGPR the HW gives 4 waves/SIMD naturally; capping to 128 caused
// catastrophic spill in R10 (WRITE_SIZE 314MB of scratch). Q stages through
// b1 then lives in registers. One barrier per tile; stage t+1 while computing t.
// XCD-bijective swizzle (512%8==0): 64 consecutive wgid (4 bh, KV 2MB) per XCD L2.
__global__ __launch_bounds__(256) void attn_flash(
    const unsigned short* __restrict__ qp,   // [B,H,T,D], pre-scaled by 0.125*log2e
    const unsigned short* __restrict__ kp,   // [B,H,S,D]
    const unsigned short* __restrict__ vtp,  // [B,H,D,S]
    unsigned short* __restrict__ attno) {    // [B*T, E]
  __shared__ __align__(16) char smem[32768];

  int tid = threadIdx.x, lane = tid & 63, wid = tid >> 6;
  int wgid = ((blockIdx.x & 7) << 6) + (blockIdx.x >> 3);  // 512 blocks, 8 XCDs
  int tt = wgid & 15, bh = wgid >> 4;
  const char* qh = (const char*)qp + ((size_t)bh * T_ + tt * 128) * 128;
  const char* kh = (const char*)kp + (size_t)bh * S_ * 128;
  const char* vh = (const char*)vtp + (size_t)bh * D_ * S_ * 2;

  int rowc = tid >> 3;
  int kswz = ((tid & 7) ^ (rowc & 7)) << 4;

#define STAGE_K(SB, IT) { \
    gl16(kh + (size_t)((IT) * 64 + rowc) * 128 + kswz, smem + (SB) + (wid << 10)); \
    gl16(kh + (size_t)((IT) * 64 + 32 + rowc) * 128 + kswz, smem + (SB) + 4096 + (wid << 10)); }
#define STAGE_V(SB, IT) { \
    gl16(vh + (size_t)rowc * 4096 + (IT) * 128 + kswz, smem + (SB) + 8192 + (wid << 10)); \
    gl16(vh + (size_t)(32 + rowc) * 4096 + (IT) * 128 + kswz, smem + (SB) + 12288 + (wid << 10)); }

  // prologue: KV0 -> b0, Q (16KB) -> b1
  STAGE_K(0, 0) STAGE_V(0, 0)
#pragma unroll
  for (int c = 0; c < 4; ++c)
    gl16(qh + (size_t)(c * 32 + rowc) * 128 + kswz, smem + 16384 + c * 4096 + (wid << 10));

  int fr = lane & 15, fg = (lane >> 4) & 3;
  int qrb = wid * 32;
  // hoisted per-lane swizzled LDS byte offsets (col bytes: ks*64 + fg*16, XOR (fr&7)<<4)
  int koff0 = fr * 128 + ((fg * 16) ^ ((fr & 7) << 4));
  int koff1 = fr * 128 + ((64 + fg * 16) ^ ((fr & 7) << 4));
  int voff[4];
#pragma unroll
  for (int ni = 0; ni < 4; ++ni)
    voff[ni] = 8192 + fr * 128 + ((ni * 32 + fg * 8) ^ ((fr & 7) << 4));

  __syncthreads();   // KV0 + Q landed (vmcnt drained)

  // Q fragments -> registers; b1 then becomes the second KV buffer
  bf16x8 qa[2][2];
#pragma unroll
  for (int mi = 0; mi < 2; ++mi) {
    qa[mi][0] = *(const bf16x8*)(smem + 16384 + (qrb + mi * 16) * 128 + koff0);
    qa[mi][1] = *(const bf16x8*)(smem + 16384 + (qrb + mi * 16) * 128 + koff1);
  }
  __syncthreads();   // ALL waves' Q reads done before b1 is overwritten

  f32x4 acco[2][4] = {};
  float lst[2] = {0.f, 0.f};

  // stage KV1 -> b1; compute tile 0 while it lands
  STAGE_K(16384, 1) STAGE_V(16384, 1)
  tile_step<0>(smem, koff0, koff1, voff, qa, acco, lst);        // t=0

#pragma unroll 1
  for (int pp = 0; pp <= 14; ++pp) {
    int ta = pp * 2;
    __syncthreads();                               // KV(ta+1) landed in b1; b0 reads done
    STAGE_K(0, ta + 2) STAGE_V(0, ta + 2)
    tile_step<16384>(smem, koff0, koff1, voff, qa, acco, lst);  // t=ta+1
    __syncthreads();                               // KV(ta+2) landed in b0; b1 reads done
    STAGE_K(16384, ta + 3) STAGE_V(16384, ta + 3)
    tile_step<0>(smem, koff0, koff1, voff, qa, acco, lst);      // t=ta+2
  }
  __syncthreads();                                 // KV31 landed in b1
  tile_step<16384>(smem, koff0, koff1, voff, qa, acco, lst);    // t=31

  // ---- epilogue: O^T lane holds q=16mi+fr, d=16nd+4fg+reg; divide by l, 8B stores
  int b = bh >> 3, h = bh & 7;
#pragma unroll
  for (int mi = 0; mi < 2; ++mi) {
    float rl = 1.0f / lst[mi];
    int t = tt * 128 + qrb + mi * 16 + fr;
    unsigned short* rowp = attno + (size_t)(b * T_ + t) * E_ + h * 64;
#pragma unroll
    for (int nd = 0; nd < 4; ++nd) {
      ushort4 o;
      o.x = f2bf(acco[mi][nd][0] * rl);
      o.y = f2bf(acco[mi][nd][1] * rl);
      o.z = f2bf(acco[mi][nd][2] * rl);
      o.w = f2bf(acco[mi][nd][3] * rl);
      *(ushort4*)(rowp + nd * 16 + fg * 4) = o;
    }
  }
#undef STAGE_K
#undef STAGE_V
}

// ---------------------------------------------------------------- launch
extern "C" void kernel_launch(void* const* d_in, const int* in_sizes, int n_in,
                              void* d_out, int out_size, void* d_ws, size_t ws_size,
                              hipStream_t stream) {
  const float* query = (const float*)d_in[0];
  const float* key_  = (const float*)d_in[1];
  const float* value = (const float*)d_in[2];
  const float* Wq    = (const float*)d_in[3];
  const float* bq    = (const float*)d_in[4];
  const float* Wk    = (const float*)d_in[5];
  const float* bk    = (const float*)d_in[6];
  const float* Wv    = (const float*)d_in[7];
  const float* bv    = (const float*)d_in[8];
  const float* Wo    = (const float*)d_in[9];
  const float* bo    = (const float*)d_in[10];
  const float* r     = (const float*)d_in[11];

  char* ws = (char*)d_ws;
  unsigned short* qb    = (unsigned short*)(ws + 0);          //  8 MiB  query bf16
  unsigned short* kb    = (unsigned short*)(ws + 8388608);    //  8 MiB  key bf16
  unsigned short* vb    = (unsigned short*)(ws + 16777216);   //  8 MiB  value bf16
  unsigned short* wqb   = (unsigned short*)(ws + 25165824);   // 512 KiB
  unsigned short* wkb   = (unsigned short*)(ws + 25690112);
  unsigned short* wvb   = (unsigned short*)(ws + 26214400);
  unsigned short* wob   = (unsigned short*)(ws + 26738688);
  unsigned short* qp    = (unsigned short*)(ws + 27262976);   //  8 MiB  [B,H,T,D]
  unsigned short* kp    = (unsigned short*)(ws + 35651584);   //  8 MiB  [B,H,S,D]
  unsigned short* vtp   = (unsigned short*)(ws + 44040192);   //  8 MiB  [B,H,D,S]
  unsigned short* attno = (unsigned short*)(ws + 52428800);   //  8 MiB  [B*T, E]

  cvt3_bf16<<<1536, 256, 0, stream>>>(query, key_, value, qb, kb, vb, (B_ * T_ * E_) / 4);
  cvt4_bf16<<<512, 256, 0, stream>>>(Wq, Wk, Wv, Wo, wqb, wkb, wvb, wob, (E_ * E_) / 4);

  const float SCLQ = 0.125f * 1.44269504089f;  // fold 1/sqrt(D) * log2(e) into Q

  // Q = logistic(query Wq^T + bq) * SCLQ  -> [B,H,T,D]
  gemm_nt<EPI_LH><<<512, 256, 0, stream>>>(qb, wqb, bq, qp, r, SCLQ, 8);
  // K = logistic(key Wk^T + bk)           -> [B,H,S,D]
  gemm_nt<EPI_LH><<<512, 256, 0, stream>>>(kb, wkb, bk, kp, r, 1.0f, 8);
  // V^T = Wv value^T + bv                 -> [B,H,D,S]  (swapped NT gemm)
  gemm_nt<EPI_VT><<<512, 256, 0, stream>>>(wvb, vb, bv, vtp, r, 1.0f, 128);

  attn_flash<<<512, 256, 0, stream>>>(qp, kp, vtp, attno);

  // out = attno Wo^T + bo  (fp32)
  gemm_nt<EPI_F32><<<512, 256, 0, stream>>>(attno, wob, bo, d_out, r, 1.0f, 8);
}